// Round 6
// baseline (127.904 us; speedup 1.0000x reference)
//
#include <hip/hip_runtime.h>

#define KTAPS 10
#define SKIP  2
#define TRANS 100
#define PAD   ((KTAPS - 1) * SKIP)   // 18
#define NFEAT 231                    // 1 + 10 + 220
#define NIN   4096
#define NT    (NIN - TRANS)          // 3996
#define NROWS 32                     // 8*4
#define CHUNK 128                    // timesteps per block
#define NCHUNK ((NT + CHUNK - 1) / CHUNK)  // 32 (31 full + tail of 28)

// Feature-major, register-direct streamer. Lane = feature f; block iterates
// its 128-timestep chunk. No LDS, no barriers: each wave emits one long run
// of independent register-sourced stores (out[t][f], lanes contiguous in f),
// so dozens of store instructions stay in flight per wave (Little's law needs
// ~23KB/CU in flight to reach ~6.3 TB/s; LDS->store chains capped us at ~4KB).
__global__ __launch_bounds__(256) void nvar_kernel(const float* __restrict__ X,
                                                   float* __restrict__ out) {
    const int f   = threadIdx.x;             // feature index; 231..255 idle
    const int row = blockIdx.y;
    const int t0  = blockIdx.x * CHUNK;
    const int tcount = min(CHUNK, NT - t0);  // 128 or 28
    if (f >= NFEAT) return;

    // Decode lane's feature -> tap offsets (runs once; lane-constant).
    // f==0: ones. f in [1,10]: lin_{f-1}. f>=11: monomial m=f-11 -> (i<=j<=l)
    // in combinations_with_replacement(range(10),3) lex order.
    const bool is_one = (f == 0);
    const bool is_lin = (f >= 1 && f <= KTAPS);
    int aoff = 0, boff = 0, coff = 0;
    if (is_lin) {
        aoff = 2 * (f - 1);
    } else if (f > KTAPS) {
        int rem = f - (KTAPS + 1);
        for (int i = 0; i < KTAPS; ++i)
            for (int j = i; j < KTAPS; ++j) {
                const int c = KTAPS - j;
                if (rem >= 0 && rem < c) { aoff = 2 * i; boff = 2 * j; coff = 2 * (j + rem); }
                rem -= c;
            }
    }

    // lin_k(t_abs) = X[row, t_abs + 82 + 2k]; max addr t0+tcount-1+82+18 <= 4095.
    const float* __restrict__ xp = X + (size_t)row * NIN + t0 + (TRANS - PAD);
    float* __restrict__ op = out + ((size_t)row * NT + t0) * NFEAT + f;

    int t = 0;
    // Unrolled-16 body: 48 independent L1-hit loads feed 16 independent
    // stores; never reads past xp[tcount-1+15+PAD] <= row end (4095).
    for (; t + 16 <= tcount; t += 16) {
#pragma unroll
        for (int u = 0; u < 16; ++u) {
            const float va = xp[aoff + t + u];
            const float vb = xp[boff + t + u];
            const float vc = xp[coff + t + u];
            const float v = is_one ? 1.0f : (is_lin ? va : va * vb * vc);
            op[(t + u) * NFEAT] = v;
        }
    }
    for (; t < tcount; ++t) {                 // tail chunk: 28 = 16 + 12
        const float va = xp[aoff + t];
        const float vb = xp[boff + t];
        const float vc = xp[coff + t];
        const float v = is_one ? 1.0f : (is_lin ? va : va * vb * vc);
        op[t * NFEAT] = v;
    }
}

extern "C" void kernel_launch(void* const* d_in, const int* in_sizes, int n_in,
                              void* d_out, int out_size, void* d_ws, size_t ws_size,
                              hipStream_t stream) {
    const float* X = (const float*)d_in[0];
    float* out = (float*)d_out;
    dim3 grid(NCHUNK, NROWS);                 // 32 x 32 = 1024 blocks, 4/CU
    nvar_kernel<<<grid, 256, 0, stream>>>(X, out);
}

// Round 8
// 127.584 us; speedup vs baseline: 1.0025x; 1.0025x over previous
//
#include <hip/hip_runtime.h>

#define KTAPS 10
#define SKIP  2
#define TRANS 100
#define PAD   ((KTAPS - 1) * SKIP)   // 18
#define NFEAT 231                    // 1 + 10 + 220
#define NIN   4096
#define NT    (NIN - TRANS)          // 3996
#define NROWS 32                     // 8*4
#define TT    32                     // timesteps per block

// Native clang vector type: __builtin_nontemporal_store requires a vector of
// scalars, not HIP's float4 struct.
typedef float v4f __attribute__((ext_vector_type(4)));

// Emit monomials for pair-index range [PLO,PHI) of the 55 i<=j pairs, fully
// unrolled so every f-offset and tap index is a compile-time constant.
// Lex order matches itertools.combinations_with_replacement(range(10), 3).
template<int PLO, int PHI, bool LIN>
__device__ __forceinline__ void emit_features(const float* __restrict__ tap,
                                              float* __restrict__ frow) {
    if (LIN) {
        frow[0] = 1.0f;
#pragma unroll
        for (int k = 0; k < KTAPS; ++k) frow[1 + k] = tap[k];
    }
    int p = 0, fb = 1 + KTAPS;
#pragma unroll
    for (int i = 0; i < KTAPS; ++i) {
#pragma unroll
        for (int j = i; j < KTAPS; ++j) {
            if (p >= PLO && p < PHI) {
                const float pij = tap[i] * tap[j];
#pragma unroll
                for (int l = j; l < KTAPS; ++l)
                    frow[fb + (l - j)] = pij * tap[l];
            }
            fb += KTAPS - j;
            ++p;
        }
    }
}

__global__ __launch_bounds__(256, 5) void nvar_kernel(const float* __restrict__ X,
                                                      float* __restrict__ out) {
    // LDS tile laid out EXACTLY like the output slab: [t][feat], stride 231.
    // 231 % 32 = 7 (odd) -> compute-phase writes are bank-conflict-free.
    // 32*231*4 = 29,568 B -> 5 blocks/CU.
    __shared__ __align__(16) float feat[TT * NFEAT];

    const int tile = blockIdx.x;
    const int row  = blockIdx.y;
    const int t0   = tile * TT;
    const int tcount = min(TT, NT - t0);         // 32 or 28 (tail)

    const int tl = threadIdx.x & 31;             // local timestep (both wave halves)
    const int wq = threadIdx.x >> 6;             // wave id, wave-uniform

    int tg = t0 + tl;
    if (tg >= NT) tg = NT - 1;                   // tail clamp; extra rows unused

    // lin_k(t) = X[row, t + 82 + 2k]; max index 3995+82+18 = 4095, in-bounds.
    const float* xrow = X + (size_t)row * NIN;
    float tap[KTAPS];
#pragma unroll
    for (int k = 0; k < KTAPS; ++k)
        tap[k] = xrow[tg + (TRANS - PAD) + 2 * k];

    // Upper/lower 32 lanes duplicate rows (identical values -> benign).
    float* frow = feat + tl * NFEAT;
    switch (wq) {                                // balanced writes: 56/55/58/62
        case 0:  emit_features< 0,  6, true >(tap, frow); break;
        case 1:  emit_features< 6, 19, false>(tap, frow); break;
        case 2:  emit_features<19, 31, false>(tap, frow); break;
        default: emit_features<31, 55, false>(tap, frow); break;
    }

    __syncthreads();

    // Flat float4 copy, NONTEMPORAL stores: stream past L3 so our 118 MB of
    // writes doesn't force synchronous eviction of the harness poison-fill's
    // dirty L3 lines (the theory for the invariant ~50 us kernel time).
    const int total4 = (tcount * NFEAT) >> 2;    // 1848 or 1617, exact
    v4f* __restrict__ o4 =
        reinterpret_cast<v4f*>(out + ((size_t)row * NT + t0) * NFEAT);
    const v4f* s4 = reinterpret_cast<const v4f*>(feat);
    for (int i = threadIdx.x; i < total4; i += 256)
        __builtin_nontemporal_store(s4[i], o4 + i);
}

extern "C" void kernel_launch(void* const* d_in, const int* in_sizes, int n_in,
                              void* d_out, int out_size, void* d_ws, size_t ws_size,
                              hipStream_t stream) {
    const float* X = (const float*)d_in[0];
    float* out = (float*)d_out;
    dim3 grid((NT + TT - 1) / TT, NROWS);        // 125 x 32 = 4000 blocks
    nvar_kernel<<<grid, 256, 0, stream>>>(X, out);
}